// Round 7
// baseline (8333.025 us; speedup 1.0000x reference)
//
#include <hip/hip_runtime.h>
#include <hip/hip_bf16.h>

#define N_NODES 100000
#define N_EDGES 600000
#define N_GRAPHS 64
#define D 128

#define NBLK_SCAN ((N_NODES + 255) / 256)  // 391

// ---------------- CSR build ----------------

__global__ void count_deg_k(const int* __restrict__ col, int* __restrict__ cnt) {
    int e = blockIdx.x * blockDim.x + threadIdx.x;
    if (e < N_EDGES) atomicAdd(&cnt[col[e]], 1);
}

__global__ __launch_bounds__(256) void partial_k(const int* __restrict__ cnt,
                                                 int* __restrict__ psum) {
    int i = blockIdx.x * 256 + threadIdx.x;
    int v = (i < N_NODES) ? cnt[i] : 0;
#pragma unroll
    for (int d = 32; d > 0; d >>= 1) v += __shfl_down(v, d, 64);
    __shared__ int ws[4];
    if ((threadIdx.x & 63) == 0) ws[threadIdx.x >> 6] = v;
    __syncthreads();
    if (threadIdx.x == 0) psum[blockIdx.x] = ws[0] + ws[1] + ws[2] + ws[3];
}

__global__ __launch_bounds__(512) void scanpart_k(int* __restrict__ psum) {
    __shared__ int ls[512];
    int t = threadIdx.x;
    int v = (t < NBLK_SCAN) ? psum[t] : 0;
    ls[t] = v;
    __syncthreads();
    for (int d = 1; d < 512; d <<= 1) {
        int u = (t >= d) ? ls[t - d] : 0;
        __syncthreads();
        ls[t] += u;
        __syncthreads();
    }
    if (t < NBLK_SCAN) psum[t] = ls[t] - v;  // exclusive
}

__global__ __launch_bounds__(256) void scan_scatter_k(const int* __restrict__ cnt,
                                                      const int* __restrict__ psum,
                                                      int* __restrict__ start) {
    int b = blockIdx.x, t = threadIdx.x;
    int i = b * 256 + t;
    int v = (i < N_NODES) ? cnt[i] : 0;
    __shared__ int ls[256];
    ls[t] = v;
    __syncthreads();
    for (int d = 1; d < 256; d <<= 1) {
        int u = (t >= d) ? ls[t - d] : 0;
        __syncthreads();
        ls[t] += u;
        __syncthreads();
    }
    int incl = ls[t];
    int off = psum[b];
    if (i < N_NODES) start[i] = off + incl - v;
    if (i == N_NODES - 1) start[N_NODES] = off + incl;
}

__global__ void fill_csr_k(const int* __restrict__ row, const int* __restrict__ col,
                           const int* __restrict__ start, int* __restrict__ fill,
                           int* __restrict__ esrc) {
    int e = blockIdx.x * blockDim.x + threadIdx.x;
    if (e < N_EDGES) {
        int c = col[e];
        int p = atomicAdd(&fill[c], 1);
        esrc[start[c] + p] = row[e];
    }
}

// ---------------- graph segment bounds (batch is sorted) ----------------

__global__ __launch_bounds__(128) void bounds_k(const int* __restrict__ batch,
                                                int* __restrict__ gstart) {
    int g = threadIdx.x;
    if (g > N_GRAPHS) return;
    int lo = 0, hi = N_NODES;
    while (lo < hi) {
        int mid = (lo + hi) >> 1;
        if (batch[mid] < g) lo = mid + 1; else hi = mid;
    }
    gstart[g] = lo;
}

// ---------------- Fused conv layer: hout = ReLU(W * (h_i + sum_src h_src) + (1+deg)*b)
// 512 threads, 128 nodes/block. LDS: W 64KB (4 swizzled [128][32] k-tiles via
// global_load_lds, issued before gather so latency hides) + agg 64KB (same
// layout, ds_write) + counts. Swizzle: chunk q of row j lives at slot q^s4(j),
// s4(j) = ((j>>3)^j)&7.

__device__ __forceinline__ void stage_w512(const float* __restrict__ W,
                                           float* lds, int tid) {
    int l = tid & 63, wv = tid >> 6;  // 8 waves
    int q = l & 7;
#pragma unroll
    for (int t = 0; t < 4; ++t) {
#pragma unroll
        for (int i = 0; i < 2; ++i) {
            int row = i * 64 + wv * 8 + (l >> 3);
            int sz = ((row >> 3) ^ row) & 7;
            const float* gp = W + row * D + t * 32 + ((q ^ sz) << 2);
            float* lp = lds + t * 4096 + i * 2048 + wv * 256;  // wave-uniform base
            __builtin_amdgcn_global_load_lds(
                (const __attribute__((address_space(1))) void*)gp,
                (__attribute__((address_space(3))) void*)lp, 16, 0, 0);
        }
    }
}

__global__ __launch_bounds__(512, 1) void fused_layer_k(
    const float* __restrict__ hin, const float* __restrict__ W,
    const float* __restrict__ bias, const int* __restrict__ start,
    const int* __restrict__ esrc, float* __restrict__ hout, int do_relu) {
    __shared__ float sW[4][4096];    // 64KB
    __shared__ float sAgg[4][4096];  // 64KB
    __shared__ float sCnt[128];
    const int tid = threadIdx.x;
    const int n0 = blockIdx.x * 128;
    const int wv = tid >> 6, l = tid & 63;

    stage_w512(W, &sW[0][0], tid);  // async; drained by the barrier below

    // ---- phase 1: gather-aggregate, 4 nodes per wave per iter (4 ILP chains)
    for (int it = 0; it < 4; ++it) {
        const int lr0 = it * 32 + wv * 4;
        const int nb = n0 + lr0;
        float2 a0{0.f, 0.f}, a1{0.f, 0.f}, a2{0.f, 0.f}, a3{0.f, 0.f};
        int d0 = 0, d1 = 0, d2 = 0, d3 = 0, s0 = 0, s1 = 0, s2 = 0, s3 = 0;
        if (nb < N_NODES) {
            s0 = start[nb]; d0 = start[nb + 1] - s0;
            a0 = *(const float2*)(hin + ((size_t)nb << 7) + 2 * l);
        }
        if (nb + 1 < N_NODES) {
            s1 = start[nb + 1]; d1 = start[nb + 2] - s1;
            a1 = *(const float2*)(hin + ((size_t)(nb + 1) << 7) + 2 * l);
        }
        if (nb + 2 < N_NODES) {
            s2 = start[nb + 2]; d2 = start[nb + 3] - s2;
            a2 = *(const float2*)(hin + ((size_t)(nb + 2) << 7) + 2 * l);
        }
        if (nb + 3 < N_NODES) {
            s3 = start[nb + 3]; d3 = start[nb + 4] - s3;
            a3 = *(const float2*)(hin + ((size_t)(nb + 3) << 7) + 2 * l);
        }
        int m = max(max(d0, d1), max(d2, d3));
        for (int k = 0; k < m; ++k) {
            if (k < d0) {
                float2 v = *(const float2*)(hin + ((size_t)esrc[s0 + k] << 7) + 2 * l);
                a0.x += v.x; a0.y += v.y;
            }
            if (k < d1) {
                float2 v = *(const float2*)(hin + ((size_t)esrc[s1 + k] << 7) + 2 * l);
                a1.x += v.x; a1.y += v.y;
            }
            if (k < d2) {
                float2 v = *(const float2*)(hin + ((size_t)esrc[s2 + k] << 7) + 2 * l);
                a2.x += v.x; a2.y += v.y;
            }
            if (k < d3) {
                float2 v = *(const float2*)(hin + ((size_t)esrc[s3 + k] << 7) + 2 * l);
                a3.x += v.x; a3.y += v.y;
            }
        }
        // swizzled LDS write: lane covers dims 2l,2l+1 -> tile l>>4, chunk (l&15)>>1
        const int tl = l >> 4, q = (l & 15) >> 1, eo = (l & 1) << 1;
        int lr = lr0;
        int sz = ((lr >> 3) ^ lr) & 7;
        *(float2*)&sAgg[tl][lr * 32 + ((q ^ sz) << 2) + eo] = a0;
        lr = lr0 + 1; sz = ((lr >> 3) ^ lr) & 7;
        *(float2*)&sAgg[tl][lr * 32 + ((q ^ sz) << 2) + eo] = a1;
        lr = lr0 + 2; sz = ((lr >> 3) ^ lr) & 7;
        *(float2*)&sAgg[tl][lr * 32 + ((q ^ sz) << 2) + eo] = a2;
        lr = lr0 + 3; sz = ((lr >> 3) ^ lr) & 7;
        *(float2*)&sAgg[tl][lr * 32 + ((q ^ sz) << 2) + eo] = a3;
        if (l == 0) {
            sCnt[lr0] = 1.f + d0; sCnt[lr0 + 1] = 1.f + d1;
            sCnt[lr0 + 2] = 1.f + d2; sCnt[lr0 + 3] = 1.f + d3;
        }
    }
    __syncthreads();  // drains ds_writes AND the stage_w512 vmcnt

    // ---- phase 2: out[rows 4ty+i][cols 4tx+r / 64+4tx+r-4] from LDS
    const int tx = tid & 15, ty = tid >> 4;  // ty 0..31
    float acc[4][8];
#pragma unroll
    for (int i = 0; i < 4; ++i)
#pragma unroll
        for (int r = 0; r < 8; ++r) acc[i][r] = 0.f;

#pragma unroll
    for (int t = 0; t < 4; ++t) {
        const float* bA = sAgg[t];
        const float* bW = sW[t];
#pragma unroll
        for (int k0 = 0; k0 < 8; ++k0) {
            float4 a[4], w[8];
#pragma unroll
            for (int i = 0; i < 4; ++i) {
                int lr = 4 * ty + i;
                int slot = k0 ^ (((lr >> 3) ^ lr) & 7);
                a[i] = *(const float4*)&bA[lr * 32 + (slot << 2)];
            }
#pragma unroll
            for (int r = 0; r < 8; ++r) {
                int j = (r < 4) ? (4 * tx + r) : (60 + 4 * tx + r);
                int slot = k0 ^ (((j >> 3) ^ j) & 7);
                w[r] = *(const float4*)&bW[j * 32 + (slot << 2)];
            }
#pragma unroll
            for (int i = 0; i < 4; ++i)
#pragma unroll
                for (int r = 0; r < 8; ++r) {
                    acc[i][r] = fmaf(a[i].x, w[r].x, acc[i][r]);
                    acc[i][r] = fmaf(a[i].y, w[r].y, acc[i][r]);
                    acc[i][r] = fmaf(a[i].z, w[r].z, acc[i][r]);
                    acc[i][r] = fmaf(a[i].w, w[r].w, acc[i][r]);
                }
        }
    }

    float bv[8];
#pragma unroll
    for (int r = 0; r < 8; ++r) {
        int j = (r < 4) ? (4 * tx + r) : (60 + 4 * tx + r);
        bv[r] = bias[j];
    }
#pragma unroll
    for (int i = 0; i < 4; ++i) {
        int lr = 4 * ty + i, n = n0 + lr;
        if (n >= N_NODES) continue;
        float c = sCnt[lr];
        float o[8];
#pragma unroll
        for (int r = 0; r < 8; ++r) {
            o[r] = fmaf(c, bv[r], acc[i][r]);
            if (do_relu) o[r] = fmaxf(o[r], 0.f);
        }
        float* orow = hout + ((size_t)n << 7);
        *(float4*)(orow + 4 * tx) = make_float4(o[0], o[1], o[2], o[3]);
        *(float4*)(orow + 64 + 4 * tx) = make_float4(o[4], o[5], o[6], o[7]);
    }
}

// ---------------- Collapsed layer 4 + pool + head ----------------
// logit_g = (1/c_g) * sum_{i in g} [ s[i] + sum_{src->i} s[src] + (1+deg_i)*beta ] + bc
// where s[i] = h3[i] . v,  v = Wc @ W4,  beta = Wc . b4.

__global__ __launch_bounds__(128) void vbeta_k(const float* __restrict__ W4,
                                               const float* __restrict__ b4,
                                               const float* __restrict__ Wc,
                                               float* __restrict__ vbeta) {
    int k = threadIdx.x;
    float acc = 0.f;
    for (int j = 0; j < D; ++j) acc = fmaf(Wc[j], W4[j * D + k], acc);
    vbeta[k] = acc;
    __shared__ float red[128];
    red[k] = Wc[k] * b4[k];
    __syncthreads();
    for (int st = 64; st > 0; st >>= 1) {
        if (k < st) red[k] += red[k + st];
        __syncthreads();
    }
    if (k == 0) vbeta[D] = red[0];
}

__global__ __launch_bounds__(256) void matvec_k(const float* __restrict__ h,
                                                const float* __restrict__ vbeta,
                                                float* __restrict__ s) {
    int wid = threadIdx.x >> 6, lane = threadIdx.x & 63;
    int row = blockIdx.x * 4 + wid;
    const float2 hv = *reinterpret_cast<const float2*>(&h[(size_t)row * D + lane * 2]);
    const float2 vv = *reinterpret_cast<const float2*>(&vbeta[lane * 2]);
    float dot = fmaf(hv.x, vv.x, hv.y * vv.y);
#pragma unroll
    for (int d = 32; d > 0; d >>= 1) dot += __shfl_down(dot, d, 64);
    if (lane == 0) s[row] = dot;
}

__global__ __launch_bounds__(256) void sagg_k(const float* __restrict__ s,
                                              const int* __restrict__ start,
                                              const int* __restrict__ esrc,
                                              const float* __restrict__ vbeta,
                                              float* __restrict__ a) {
    int i = blockIdx.x * 256 + threadIdx.x;
    if (i >= N_NODES) return;
    int s0 = start[i], s1 = start[i + 1];
    float beta = vbeta[D];
    float acc = s[i] + (float)(1 + s1 - s0) * beta;
    for (int e = s0; e < s1; ++e) acc += s[esrc[e]];
    a[i] = acc;
}

__global__ __launch_bounds__(256) void spool_k(const float* __restrict__ a,
                                               const int* __restrict__ gstart,
                                               const float* __restrict__ bc,
                                               float* __restrict__ out) {
    int g = blockIdx.x;
    int lo = gstart[g], hi = gstart[g + 1];
    float acc = 0.f;
    for (int i = lo + threadIdx.x; i < hi; i += 256) acc += a[i];
    __shared__ float red[256];
    red[threadIdx.x] = acc;
    __syncthreads();
    for (int st = 128; st > 0; st >>= 1) {
        if (threadIdx.x < st) red[threadIdx.x] += red[threadIdx.x + st];
        __syncthreads();
    }
    if (threadIdx.x == 0) {
        float c = (float)max(hi - lo, 1);
        out[g] = 1.f / (1.f + expf(-(red[0] / c + bc[0])));
    }
}

// ---------------- Launch ----------------

extern "C" void kernel_launch(void* const* d_in, const int* in_sizes, int n_in,
                              void* d_out, int out_size, void* d_ws, size_t ws_size,
                              hipStream_t stream) {
    const float* x   = (const float*)d_in[0];
    const int* ei    = (const int*)d_in[1];
    const int* batch = (const int*)d_in[2];
    const float* W1  = (const float*)d_in[3];
    const float* b1  = (const float*)d_in[4];
    const float* W2  = (const float*)d_in[5];
    const float* b2  = (const float*)d_in[6];
    const float* W3  = (const float*)d_in[7];
    const float* b3  = (const float*)d_in[8];
    const float* W4  = (const float*)d_in[9];
    const float* b4  = (const float*)d_in[10];
    const float* Wc  = (const float*)d_in[11];
    const float* bc  = (const float*)d_in[12];
    float* out = (float*)d_out;

    const int* row = ei;             // sources
    const int* col = ei + N_EDGES;   // targets

    char* p = (char*)d_ws;
    float* t = (float*)p;      p += (size_t)N_NODES * D * 4;   // 51.2 MB
    float* h = (float*)p;      p += (size_t)N_NODES * D * 4;   // 51.2 MB
    int* esrc = (int*)p;       p += (size_t)N_EDGES * 4;
    int* cstart = (int*)p;     p += ((N_NODES + 1) * 4 + 15) / 16 * 16;
    int* cfill = (int*)p;      p += (size_t)N_NODES * 4;
    int* psum = (int*)p;       p += ((NBLK_SCAN + 3) / 4) * 16;
    int* gstart = (int*)p;     p += 256;

    // scalar-path scratch lives in h (free after layer 3 writes t)
    float* vbeta = h;
    float* s_arr = h + 256;
    float* a_arr = h + 256 + N_NODES;

    // ---- CSR build ----
    hipMemsetAsync(cfill, 0, (size_t)N_NODES * 4, stream);
    count_deg_k<<<(N_EDGES + 255) / 256, 256, 0, stream>>>(col, cfill);
    partial_k<<<NBLK_SCAN, 256, 0, stream>>>(cfill, psum);
    scanpart_k<<<1, 512, 0, stream>>>(psum);
    scan_scatter_k<<<NBLK_SCAN, 256, 0, stream>>>(cfill, psum, cstart);
    hipMemsetAsync(cfill, 0, (size_t)N_NODES * 4, stream);
    fill_csr_k<<<(N_EDGES + 255) / 256, 256, 0, stream>>>(row, col, cstart, cfill, esrc);

    // ---- graph bounds ----
    bounds_k<<<1, 128, 0, stream>>>(batch, gstart);

    const int fgrid = (N_NODES + 127) / 128;  // 782

    // ---- Fused layers 1-3 (aggregate-then-transform, exact by linearity) ----
    fused_layer_k<<<fgrid, 512, 0, stream>>>(x, W1, b1, cstart, esrc, t, 1);
    fused_layer_k<<<fgrid, 512, 0, stream>>>(t, W2, b2, cstart, esrc, h, 1);
    fused_layer_k<<<fgrid, 512, 0, stream>>>(h, W3, b3, cstart, esrc, t, 1);

    // ---- Collapsed layer 4 + pool + head (reads t = h3) ----
    vbeta_k<<<1, 128, 0, stream>>>(W4, b4, Wc, vbeta);
    matvec_k<<<N_NODES / 4, 256, 0, stream>>>(t, vbeta, s_arr);
    sagg_k<<<(N_NODES + 255) / 256, 256, 0, stream>>>(s_arr, cstart, esrc, vbeta, a_arr);
    spool_k<<<N_GRAPHS, 256, 0, stream>>>(a_arr, gstart, bc, out);
}

// Round 8
// 473.484 us; speedup vs baseline: 17.5994x; 17.5994x over previous
//
#include <hip/hip_runtime.h>
#include <hip/hip_bf16.h>

#define N_NODES 100000
#define N_EDGES 600000
#define N_GRAPHS 64
#define D 128

#define NBLK_SCAN ((N_NODES + 255) / 256)  // 391

// ---------------- CSR build ----------------

__global__ void count_deg_k(const int* __restrict__ col, int* __restrict__ cnt) {
    int e = blockIdx.x * blockDim.x + threadIdx.x;
    if (e < N_EDGES) atomicAdd(&cnt[col[e]], 1);
}

__global__ __launch_bounds__(256) void partial_k(const int* __restrict__ cnt,
                                                 int* __restrict__ psum) {
    int i = blockIdx.x * 256 + threadIdx.x;
    int v = (i < N_NODES) ? cnt[i] : 0;
#pragma unroll
    for (int d = 32; d > 0; d >>= 1) v += __shfl_down(v, d, 64);
    __shared__ int ws[4];
    if ((threadIdx.x & 63) == 0) ws[threadIdx.x >> 6] = v;
    __syncthreads();
    if (threadIdx.x == 0) psum[blockIdx.x] = ws[0] + ws[1] + ws[2] + ws[3];
}

__global__ __launch_bounds__(512) void scanpart_k(int* __restrict__ psum) {
    __shared__ int ls[512];
    int t = threadIdx.x;
    int v = (t < NBLK_SCAN) ? psum[t] : 0;
    ls[t] = v;
    __syncthreads();
    for (int d = 1; d < 512; d <<= 1) {
        int u = (t >= d) ? ls[t - d] : 0;
        __syncthreads();
        ls[t] += u;
        __syncthreads();
    }
    if (t < NBLK_SCAN) psum[t] = ls[t] - v;  // exclusive
}

__global__ __launch_bounds__(256) void scan_scatter_k(const int* __restrict__ cnt,
                                                      const int* __restrict__ psum,
                                                      int* __restrict__ start) {
    int b = blockIdx.x, t = threadIdx.x;
    int i = b * 256 + t;
    int v = (i < N_NODES) ? cnt[i] : 0;
    __shared__ int ls[256];
    ls[t] = v;
    __syncthreads();
    for (int d = 1; d < 256; d <<= 1) {
        int u = (t >= d) ? ls[t - d] : 0;
        __syncthreads();
        ls[t] += u;
        __syncthreads();
    }
    int incl = ls[t];
    int off = psum[b];
    if (i < N_NODES) start[i] = off + incl - v;
    if (i == N_NODES - 1) start[N_NODES] = off + incl;
}

__global__ void fill_csr_k(const int* __restrict__ row, const int* __restrict__ col,
                           const int* __restrict__ start, int* __restrict__ fill,
                           int* __restrict__ esrc) {
    int e = blockIdx.x * blockDim.x + threadIdx.x;
    if (e < N_EDGES) {
        int c = col[e];
        int p = atomicAdd(&fill[c], 1);
        esrc[start[c] + p] = row[e];
    }
}

// ---------------- graph segment bounds (batch is sorted) ----------------

__global__ __launch_bounds__(128) void bounds_k(const int* __restrict__ batch,
                                                int* __restrict__ gstart) {
    int g = threadIdx.x;
    if (g > N_GRAPHS) return;
    int lo = 0, hi = N_NODES;
    while (lo < hi) {
        int mid = (lo + hi) >> 1;
        if (batch[mid] < g) lo = mid + 1; else hi = mid;
    }
    gstart[g] = lo;
}

// ---------------- GEMM (round-3 known-good: 70us) ----------------
// out[i][j] = bias[j] + sum_k in[i][k]*W[j][k]

#define BM 128
#define BK 32

__global__ __launch_bounds__(256) void gemm_k(const float* __restrict__ A,
                                              const float* __restrict__ W,
                                              const float* __restrict__ bias,
                                              float* __restrict__ out, int nrows) {
    __shared__ float sA[BK][BM + 4];
    __shared__ float sB[BK][D + 4];
    int tid = threadIdx.x;
    int bm0 = blockIdx.x * BM;
    int tx = tid & 15, ty = tid >> 4;

    float acc[8][8];
#pragma unroll
    for (int i = 0; i < 8; ++i)
#pragma unroll
        for (int j = 0; j < 8; ++j) acc[i][j] = 0.f;

    float bv[8];
#pragma unroll
    for (int j = 0; j < 8; ++j) bv[j] = bias[tx * 8 + j];

    int lr = tid >> 3;   // 0..31
    int lc4 = tid & 7;   // float4 index within 32-float K-slab

    for (int kb = 0; kb < D; kb += BK) {
#pragma unroll
        for (int rr = 0; rr < 4; ++rr) {
            int rowl = lr + rr * 32;
            int grow = bm0 + rowl;
            float4 v = make_float4(0.f, 0.f, 0.f, 0.f);
            if (grow < nrows)
                v = *reinterpret_cast<const float4*>(&A[(size_t)grow * D + kb + lc4 * 4]);
            sA[lc4 * 4 + 0][rowl] = v.x;
            sA[lc4 * 4 + 1][rowl] = v.y;
            sA[lc4 * 4 + 2][rowl] = v.z;
            sA[lc4 * 4 + 3][rowl] = v.w;
        }
#pragma unroll
        for (int rr = 0; rr < 4; ++rr) {
            int j = lr + rr * 32;
            float4 v = *reinterpret_cast<const float4*>(&W[(size_t)j * D + kb + lc4 * 4]);
            sB[lc4 * 4 + 0][j] = v.x;
            sB[lc4 * 4 + 1][j] = v.y;
            sB[lc4 * 4 + 2][j] = v.z;
            sB[lc4 * 4 + 3][j] = v.w;
        }
        __syncthreads();
#pragma unroll
        for (int k = 0; k < BK; ++k) {
            float a[8], b[8];
            *reinterpret_cast<float4*>(&a[0]) = *reinterpret_cast<const float4*>(&sA[k][ty * 8]);
            *reinterpret_cast<float4*>(&a[4]) = *reinterpret_cast<const float4*>(&sA[k][ty * 8 + 4]);
            *reinterpret_cast<float4*>(&b[0]) = *reinterpret_cast<const float4*>(&sB[k][tx * 8]);
            *reinterpret_cast<float4*>(&b[4]) = *reinterpret_cast<const float4*>(&sB[k][tx * 8 + 4]);
#pragma unroll
            for (int i = 0; i < 8; ++i)
#pragma unroll
                for (int j = 0; j < 8; ++j) acc[i][j] = fmaf(a[i], b[j], acc[i][j]);
        }
        __syncthreads();
    }

#pragma unroll
    for (int i = 0; i < 8; ++i) {
        int grow = bm0 + ty * 8 + i;
        if (grow >= nrows) continue;
        float4 o0 = make_float4(acc[i][0] + bv[0], acc[i][1] + bv[1],
                                acc[i][2] + bv[2], acc[i][3] + bv[3]);
        float4 o1 = make_float4(acc[i][4] + bv[4], acc[i][5] + bv[5],
                                acc[i][6] + bv[6], acc[i][7] + bv[7]);
        *reinterpret_cast<float4*>(&out[(size_t)grow * D + tx * 8]) = o0;
        *reinterpret_cast<float4*>(&out[(size_t)grow * D + tx * 8 + 4]) = o1;
    }
}

// ---------------- Aggregation: out[i] = t[i] + sum_{e: col==i} t[src[e]] ----------------

__global__ __launch_bounds__(128) void aggregate_k(const float* __restrict__ t,
                                                   const int* __restrict__ start,
                                                   const int* __restrict__ esrc,
                                                   float* __restrict__ out, int do_relu) {
    int node = blockIdx.x;
    int d = threadIdx.x;
    int s = start[node], e = start[node + 1];
    float acc = t[(size_t)node * D + d];  // self loop
    int i = s;
    for (; i + 1 < e; i += 2) {
        int s0 = esrc[i], s1 = esrc[i + 1];
        float a = t[(size_t)s0 * D + d];
        float b = t[(size_t)s1 * D + d];
        acc += a + b;
    }
    if (i < e) acc += t[(size_t)esrc[i] * D + d];
    if (do_relu) acc = fmaxf(acc, 0.f);
    out[(size_t)node * D + d] = acc;
}

// ---------------- Collapsed layer 4 + pool + head ----------------
// logit_g = (1/c_g) * sum_{i in g} [ s[i] + sum_{src->i} s[src] + (1+deg_i)*beta ] + bc
// where s[i] = h3[i] . v,  v = Wc @ W4,  beta = Wc . b4.

__global__ __launch_bounds__(128) void vbeta_k(const float* __restrict__ W4,
                                               const float* __restrict__ b4,
                                               const float* __restrict__ Wc,
                                               float* __restrict__ vbeta) {
    int k = threadIdx.x;
    float acc = 0.f;
    for (int j = 0; j < D; ++j) acc = fmaf(Wc[j], W4[j * D + k], acc);
    vbeta[k] = acc;
    __shared__ float red[128];
    red[k] = Wc[k] * b4[k];
    __syncthreads();
    for (int st = 64; st > 0; st >>= 1) {
        if (k < st) red[k] += red[k + st];
        __syncthreads();
    }
    if (k == 0) vbeta[D] = red[0];
}

__global__ __launch_bounds__(256) void matvec_k(const float* __restrict__ h,
                                                const float* __restrict__ vbeta,
                                                float* __restrict__ s) {
    int wid = threadIdx.x >> 6, lane = threadIdx.x & 63;
    int row = blockIdx.x * 4 + wid;
    const float2 hv = *reinterpret_cast<const float2*>(&h[(size_t)row * D + lane * 2]);
    const float2 vv = *reinterpret_cast<const float2*>(&vbeta[lane * 2]);
    float dot = fmaf(hv.x, vv.x, hv.y * vv.y);
#pragma unroll
    for (int d = 32; d > 0; d >>= 1) dot += __shfl_down(dot, d, 64);
    if (lane == 0) s[row] = dot;
}

__global__ __launch_bounds__(256) void sagg_k(const float* __restrict__ s,
                                              const int* __restrict__ start,
                                              const int* __restrict__ esrc,
                                              const float* __restrict__ vbeta,
                                              float* __restrict__ a) {
    int i = blockIdx.x * 256 + threadIdx.x;
    if (i >= N_NODES) return;
    int s0 = start[i], s1 = start[i + 1];
    float beta = vbeta[D];
    float acc = s[i] + (float)(1 + s1 - s0) * beta;
    for (int e = s0; e < s1; ++e) acc += s[esrc[e]];
    a[i] = acc;
}

__global__ __launch_bounds__(256) void spool_k(const float* __restrict__ a,
                                               const int* __restrict__ gstart,
                                               const float* __restrict__ bc,
                                               float* __restrict__ out) {
    int g = blockIdx.x;
    int lo = gstart[g], hi = gstart[g + 1];
    float acc = 0.f;
    for (int i = lo + threadIdx.x; i < hi; i += 256) acc += a[i];
    __shared__ float red[256];
    red[threadIdx.x] = acc;
    __syncthreads();
    for (int st = 128; st > 0; st >>= 1) {
        if (threadIdx.x < st) red[threadIdx.x] += red[threadIdx.x + st];
        __syncthreads();
    }
    if (threadIdx.x == 0) {
        float c = (float)max(hi - lo, 1);
        out[g] = 1.f / (1.f + expf(-(red[0] / c + bc[0])));
    }
}

// ---------------- Launch ----------------

extern "C" void kernel_launch(void* const* d_in, const int* in_sizes, int n_in,
                              void* d_out, int out_size, void* d_ws, size_t ws_size,
                              hipStream_t stream) {
    const float* x   = (const float*)d_in[0];
    const int* ei    = (const int*)d_in[1];
    const int* batch = (const int*)d_in[2];
    const float* W1  = (const float*)d_in[3];
    const float* b1  = (const float*)d_in[4];
    const float* W2  = (const float*)d_in[5];
    const float* b2  = (const float*)d_in[6];
    const float* W3  = (const float*)d_in[7];
    const float* b3  = (const float*)d_in[8];
    const float* W4  = (const float*)d_in[9];
    const float* b4  = (const float*)d_in[10];
    const float* Wc  = (const float*)d_in[11];
    const float* bc  = (const float*)d_in[12];
    float* out = (float*)d_out;

    const int* row = ei;             // sources
    const int* col = ei + N_EDGES;   // targets

    char* p = (char*)d_ws;
    float* t = (float*)p;      p += (size_t)N_NODES * D * 4;   // 51.2 MB
    float* h = (float*)p;      p += (size_t)N_NODES * D * 4;   // 51.2 MB
    int* esrc = (int*)p;       p += (size_t)N_EDGES * 4;
    int* cstart = (int*)p;     p += ((N_NODES + 1) * 4 + 15) / 16 * 16;
    int* cfill = (int*)p;      p += (size_t)N_NODES * 4;
    int* psum = (int*)p;       p += ((NBLK_SCAN + 3) / 4) * 16;
    int* gstart = (int*)p;     p += 256;

    // scalar-path scratch lives in t (free after layer-3 aggregate consumes it)
    float* vbeta = t;
    float* s_arr = t + 256;
    float* a_arr = t + 256 + N_NODES;

    // ---- CSR build ----
    hipMemsetAsync(cfill, 0, (size_t)N_NODES * 4, stream);
    count_deg_k<<<(N_EDGES + 255) / 256, 256, 0, stream>>>(col, cfill);
    partial_k<<<NBLK_SCAN, 256, 0, stream>>>(cfill, psum);
    scanpart_k<<<1, 512, 0, stream>>>(psum);
    scan_scatter_k<<<NBLK_SCAN, 256, 0, stream>>>(cfill, psum, cstart);
    hipMemsetAsync(cfill, 0, (size_t)N_NODES * 4, stream);
    fill_csr_k<<<(N_EDGES + 255) / 256, 256, 0, stream>>>(row, col, cstart, cfill, esrc);

    // ---- graph bounds ----
    bounds_k<<<1, 128, 0, stream>>>(batch, gstart);

    const int ggrid = (N_NODES + BM - 1) / BM;  // 782

    // ---- Layers 1-3 ----
    gemm_k<<<ggrid, 256, 0, stream>>>(x, W1, b1, t, N_NODES);
    aggregate_k<<<N_NODES, 128, 0, stream>>>(t, cstart, esrc, h, 1);
    gemm_k<<<ggrid, 256, 0, stream>>>(h, W2, b2, t, N_NODES);
    aggregate_k<<<N_NODES, 128, 0, stream>>>(t, cstart, esrc, h, 1);
    gemm_k<<<ggrid, 256, 0, stream>>>(h, W3, b3, t, N_NODES);
    aggregate_k<<<N_NODES, 128, 0, stream>>>(t, cstart, esrc, h, 1);

    // ---- Collapsed layer 4 + pool + head (reads h = h3) ----
    vbeta_k<<<1, 128, 0, stream>>>(W4, b4, Wc, vbeta);
    matvec_k<<<N_NODES / 4, 256, 0, stream>>>(h, vbeta, s_arr);
    sagg_k<<<(N_NODES + 255) / 256, 256, 0, stream>>>(s_arr, cstart, esrc, vbeta, a_arr);
    spool_k<<<N_GRAPHS, 256, 0, stream>>>(a_arr, gstart, bc, out);
}